// Round 2
// baseline (506.822 us; speedup 1.0000x reference)
//
#include <hip/hip_runtime.h>

// Inverse 2D DWT, single level, fused column+row synthesis. FP32 throughout.
// Inputs ss,sd,ds,dd: (B,C,H,W) f32; h,g: (6,) f32. Output: (B,C,2H,2W) f32.
// out[2i+py][2j+px] = sum_{dy,dx in {-1,0,1}}
//   wh[py][dy]*wh[px][dx]*ss + wg[py][dy]*wh[px][dx]*sd
// + wh[py][dy]*wg[px][dx]*ds + wg[py][dy]*wg[px][dx]*dd
// with wh[0] = (h4,h2,h0), wh[1] = (h5,h3,h1) over dy=(-1,0,+1); reflect pad 1.

typedef float float4v __attribute__((ext_vector_type(4)));

constexpr int Hc = 256;
constexpr int Wc = 256;

__global__ __launch_bounds__(256) void idwt_kernel(
    const float* __restrict__ ss, const float* __restrict__ sd,
    const float* __restrict__ ds, const float* __restrict__ dd,
    const float* __restrict__ hf, const float* __restrict__ gf,
    float* __restrict__ out)
{
    const int tx = threadIdx.x;            // 0..63 -> j0 = 4*tx
    const int ty = threadIdx.y;            // 0..3
    const int i  = blockIdx.x * 4 + ty;    // 0..H-1
    const int bc = blockIdx.y;             // 0..B*C-1

    const float h0 = hf[0], h1 = hf[1], h2 = hf[2];
    const float h3 = hf[3], h4 = hf[4], h5 = hf[5];
    const float g0 = gf[0], g1 = gf[1], g2 = gf[2];
    const float g3 = gf[3], g4 = gf[4], g5 = gf[5];

    const size_t off = (size_t)bc * (Hc * Wc);
    const float* pss = ss + off;
    const float* psd = sd + off;
    const float* pds = ds + off;
    const float* pdd = dd + off;

    // reflect-1 row indices
    const int r0 = (i == 0) ? 1 : i - 1;
    const int r1 = i;
    const int r2 = (i == Hc - 1) ? Hc - 2 : i + 1;

    const int j0 = tx * 4;
    const int cm = (j0 == 0) ? 1 : j0 - 1;            // reflect left
    const int cp = (j0 + 4 == Wc) ? Wc - 2 : j0 + 4;  // reflect right

    auto load6 = [&](const float* base, int r, float dst[6]) {
        const float* rp = base + (size_t)r * Wc;
        const float4v m = *reinterpret_cast<const float4v*>(rp + j0);
        dst[0] = rp[cm];
        dst[1] = m[0]; dst[2] = m[1];
        dst[3] = m[2]; dst[4] = m[3];
        dst[5] = rp[cp];
    };

    // vertical (column synthesis) results for 6 columns
    float vs0[6], vs1[6], vd0[6], vd1[6];
    {
        float a0[6], a1[6], a2[6], b0[6], b1[6], b2[6];
        load6(pss, r0, a0); load6(pss, r1, a1); load6(pss, r2, a2);
        load6(psd, r0, b0); load6(psd, r1, b1); load6(psd, r2, b2);
        #pragma unroll
        for (int k = 0; k < 6; ++k) {
            vs0[k] = h4*a0[k] + h2*a1[k] + h0*a2[k] + g4*b0[k] + g2*b1[k] + g0*b2[k];
            vs1[k] = h5*a0[k] + h3*a1[k] + h1*a2[k] + g5*b0[k] + g3*b1[k] + g1*b2[k];
        }
    }
    {
        float a0[6], a1[6], a2[6], b0[6], b1[6], b2[6];
        load6(pds, r0, a0); load6(pds, r1, a1); load6(pds, r2, a2);
        load6(pdd, r0, b0); load6(pdd, r1, b1); load6(pdd, r2, b2);
        #pragma unroll
        for (int k = 0; k < 6; ++k) {
            vd0[k] = h4*a0[k] + h2*a1[k] + h0*a2[k] + g4*b0[k] + g2*b1[k] + g0*b2[k];
            vd1[k] = h5*a0[k] + h3*a1[k] + h1*a2[k] + g5*b0[k] + g3*b1[k] + g1*b2[k];
        }
    }

    // horizontal (row synthesis): 2 output rows x 8 output cols
    float o0[8], o1[8];
    #pragma unroll
    for (int t = 0; t < 4; ++t) {
        o0[2*t]   = h4*vs0[t] + h2*vs0[t+1] + h0*vs0[t+2] + g4*vd0[t] + g2*vd0[t+1] + g0*vd0[t+2];
        o0[2*t+1] = h5*vs0[t] + h3*vs0[t+1] + h1*vs0[t+2] + g5*vd0[t] + g3*vd0[t+1] + g1*vd0[t+2];
        o1[2*t]   = h4*vs1[t] + h2*vs1[t+1] + h0*vs1[t+2] + g4*vd1[t] + g2*vd1[t+1] + g0*vd1[t+2];
        o1[2*t+1] = h5*vs1[t] + h3*vs1[t+1] + h1*vs1[t+2] + g5*vd1[t] + g3*vd1[t+1] + g1*vd1[t+2];
    }

    const int W2 = 2 * Wc;
    float* orow0 = out + ((size_t)bc * (2 * Hc) + (2 * i)) * W2 + 8 * tx;
    float* orow1 = orow0 + W2;

    *reinterpret_cast<float4v*>(orow0)     = float4v{o0[0], o0[1], o0[2], o0[3]};
    *reinterpret_cast<float4v*>(orow0 + 4) = float4v{o0[4], o0[5], o0[6], o0[7]};
    *reinterpret_cast<float4v*>(orow1)     = float4v{o1[0], o1[1], o1[2], o1[3]};
    *reinterpret_cast<float4v*>(orow1 + 4) = float4v{o1[4], o1[5], o1[6], o1[7]};
}

extern "C" void kernel_launch(void* const* d_in, const int* in_sizes, int n_in,
                              void* d_out, int out_size, void* d_ws, size_t ws_size,
                              hipStream_t stream) {
    const float* ss = (const float*)d_in[0];
    const float* sd = (const float*)d_in[1];
    const float* ds = (const float*)d_in[2];
    const float* dd = (const float*)d_in[3];
    const float* hf = (const float*)d_in[4];
    const float* gf = (const float*)d_in[5];
    float* out = (float*)d_out;

    const int BC = in_sizes[0] / (Hc * Wc);   // B*C = 256
    dim3 block(64, 4);                         // 64 j-tiles x 4 rows
    dim3 grid(Hc / 4, BC);                     // x fastest -> adjacent i-tiles share rows in L2
    idwt_kernel<<<grid, block, 0, stream>>>(ss, sd, ds, dd, hf, gf, out);
}